// Round 8
// baseline (351.049 us; speedup 1.0000x reference)
//
#include <hip/hip_runtime.h>
#include <math.h>

constexpr int N_NODES = 20000;
constexpr int DIM = 512;       // NODE_DIM == HIDDEN
constexpr int NG = 64;
constexpr int KCH = 128;       // U-GEMM k-chunk
constexpr int NCHUNK = (N_NODES + KCH - 1) / KCH;  // 157 (last chunk kmax=32, %4==0)
constexpr int SCAN_THREADS = 1024;
constexpr int SCAN_CHUNK = 20; // 1024*20 = 20480 >= 20000

// ---------------- misc ----------------
__device__ __forceinline__ int lower_bound_i(const int* __restrict__ a, int n, int v) {
  int lo = 0, hi = n;
  while (lo < hi) {
    int mid = (lo + hi) >> 1;
    if (a[mid] < v) lo = mid + 1; else hi = mid;
  }
  return lo;
}

// wT[j][g] = [batch[j]==g]; counts[j]=0; ng/eh init (block 0)
__global__ __launch_bounds__(256) void node_init(const int* __restrict__ batch,
                                                 float* __restrict__ wT,
                                                 int* __restrict__ counts,
                                                 float* __restrict__ ng,
                                                 float* __restrict__ eh, int n_nodes) {
  int node = blockIdx.x * 4 + (threadIdx.x >> 6);
  int g = threadIdx.x & 63;
  if (node < n_nodes) {
    int b = batch[node];
    wT[(size_t)node * 64 + g] = (g == b) ? 1.f : 0.f;
    if (g == 0) counts[node] = 0;
  }
  if (blockIdx.x == 0 && threadIdx.x < 64) {
    int gg = threadIdx.x;
    int s0 = lower_bound_i(batch, n_nodes, gg);
    int e0 = lower_bound_i(batch, n_nodes, gg + 1);
    ng[gg] = (float)(e0 - s0);
    eh[gg] = 0.f;
  }
}

// edge pass: wT[src][batch[dst]] += 1; counts[src] += 1; eh hist (LDS)
__global__ __launch_bounds__(256) void edge_pass(const int* __restrict__ srcI,
                                                 const int* __restrict__ dstI,
                                                 const int* __restrict__ batch,
                                                 float* __restrict__ wT,
                                                 int* __restrict__ counts,
                                                 float* __restrict__ eh, int n_edges) {
  __shared__ int hist[64];
  int t = threadIdx.x;
  if (t < 64) hist[t] = 0;
  __syncthreads();
  int i = blockIdx.x * 256 + t;
  int stride = gridDim.x * 256;
  for (; i < n_edges; i += stride) {
    int s = srcI[i];
    int b = batch[dstI[i]];
    atomicAdd(&wT[(size_t)s * 64 + b], 1.f);
    atomicAdd(&counts[s], 1);
    atomicAdd(&hist[b], 1);
  }
  __syncthreads();
  if (t < 64 && hist[t] != 0) atomicAdd(&eh[t], (float)hist[t]);
}

// ---------------- CSR scan (shfl-based, single block) ----------------
__global__ __launch_bounds__(SCAN_THREADS) void scan_counts(const int* __restrict__ counts,
                                                            int* __restrict__ rowptr,
                                                            int* __restrict__ cursor, int n) {
  int t = threadIdx.x;
  int lane = t & 63;
  int wave = t >> 6;  // 0..15
  int base = t * SCAN_CHUNK;
  int partial = 0;
#pragma unroll
  for (int j = 0; j < SCAN_CHUNK; ++j) {
    int idx = base + j;
    if (idx < n) partial += counts[idx];
  }
  int incl = partial;
  for (int off = 1; off < 64; off <<= 1) {
    int v = __shfl_up(incl, off, 64);
    if (lane >= off) incl += v;
  }
  __shared__ int wsum[16];
  if (lane == 63) wsum[wave] = incl;
  __syncthreads();
  if (wave == 0 && lane < 16) {
    int v = wsum[lane];
    int wincl = v;
    for (int off = 1; off < 16; off <<= 1) {
      int u = __shfl_up(wincl, off, 64);
      if (lane >= off) wincl += u;
    }
    wsum[lane] = wincl - v;  // exclusive wave offset
  }
  __syncthreads();
  int run = incl - partial + wsum[wave];
#pragma unroll
  for (int j = 0; j < SCAN_CHUNK; ++j) {
    int idx = base + j;
    if (idx < n) {
      rowptr[idx] = run;
      cursor[idx] = run;
      run += counts[idx];
    }
  }
  if (t == SCAN_THREADS - 1) rowptr[n] = run;
}

__global__ void fill_csr(const int* __restrict__ srcI, const int* __restrict__ dstI,
                         int* __restrict__ cursor, int* __restrict__ edst, int n_edges) {
  int i = blockIdx.x * blockDim.x + threadIdx.x;
  int stride = gridDim.x * blockDim.x;
  for (; i < n_edges; i += stride) {
    int pos = atomicAdd(&cursor[srcI[i]], 1);
    edst[pos] = dstI[i];
  }
}

// ---------------- cT[k][g] = wT[k][g] + sum_{e:src=k} wT[dst(e)][g] ----------------
__global__ __launch_bounds__(256) void compute_cT(const float* __restrict__ wT,
                                                  const int* __restrict__ rowptr,
                                                  const int* __restrict__ edst,
                                                  float* __restrict__ cT, int n_nodes) {
  int node = blockIdx.x * 4 + (threadIdx.x >> 6);
  int g = threadIdx.x & 63;
  if (node >= n_nodes) return;
  float acc = wT[(size_t)node * 64 + g];
  int beg = rowptr[node];
  int end = rowptr[node + 1];
  for (int i = beg; i < end; ++i) {
    int d = edst[i];
    acc += wT[(size_t)d * 64 + g];
  }
  cT[(size_t)node * 64 + g] = acc;
}

// ---------------- U-GEMM: Upart[c][g][n] = sum_{k in chunk c} cT[k][g]*x[k][n] ----------------
__global__ __launch_bounds__(256) void ugemm(const float* __restrict__ x,
                                             const float* __restrict__ cT,
                                             float* __restrict__ Upart) {
  __shared__ float sc[KCH][64];  // 32 KB
  int t = threadIdx.x;
  int k0 = blockIdx.y * KCH;
  int kmax = (N_NODES - k0) < KCH ? (N_NODES - k0) : KCH;  // 128 or 32; %4==0
  {
    const float4* src = (const float4*)(cT + (size_t)k0 * 64);
    float4* dst = (float4*)(&sc[0][0]);
    int limit4 = kmax * 16;
    for (int i = t; i < limit4; i += 256) dst[i] = src[i];
  }
  __syncthreads();
  int lane = t & 63;
  int slice = t >> 6;                 // g-range [slice*16, slice*16+16)
  int n2 = blockIdx.x * 64 + lane;    // float2 col 0..255
  const float2* x2 = (const float2*)x;
  float2 acc[16];
#pragma unroll
  for (int j = 0; j < 16; ++j) acc[j] = make_float2(0.f, 0.f);
  for (int kk = 0; kk < kmax; kk += 4) {
    float2 xv[4];
#pragma unroll
    for (int u = 0; u < 4; ++u)
      xv[u] = x2[(size_t)(k0 + kk + u) * 256 + n2];
#pragma unroll
    for (int u = 0; u < 4; ++u) {
      const float4* cp = (const float4*)&sc[kk + u][slice * 16];
      float4 c0 = cp[0], c1 = cp[1], c2 = cp[2], c3 = cp[3];
      float2 xu = xv[u];
      acc[0].x  = fmaf(c0.x, xu.x, acc[0].x);  acc[0].y  = fmaf(c0.x, xu.y, acc[0].y);
      acc[1].x  = fmaf(c0.y, xu.x, acc[1].x);  acc[1].y  = fmaf(c0.y, xu.y, acc[1].y);
      acc[2].x  = fmaf(c0.z, xu.x, acc[2].x);  acc[2].y  = fmaf(c0.z, xu.y, acc[2].y);
      acc[3].x  = fmaf(c0.w, xu.x, acc[3].x);  acc[3].y  = fmaf(c0.w, xu.y, acc[3].y);
      acc[4].x  = fmaf(c1.x, xu.x, acc[4].x);  acc[4].y  = fmaf(c1.x, xu.y, acc[4].y);
      acc[5].x  = fmaf(c1.y, xu.x, acc[5].x);  acc[5].y  = fmaf(c1.y, xu.y, acc[5].y);
      acc[6].x  = fmaf(c1.z, xu.x, acc[6].x);  acc[6].y  = fmaf(c1.z, xu.y, acc[6].y);
      acc[7].x  = fmaf(c1.w, xu.x, acc[7].x);  acc[7].y  = fmaf(c1.w, xu.y, acc[7].y);
      acc[8].x  = fmaf(c2.x, xu.x, acc[8].x);  acc[8].y  = fmaf(c2.x, xu.y, acc[8].y);
      acc[9].x  = fmaf(c2.y, xu.x, acc[9].x);  acc[9].y  = fmaf(c2.y, xu.y, acc[9].y);
      acc[10].x = fmaf(c2.z, xu.x, acc[10].x); acc[10].y = fmaf(c2.z, xu.y, acc[10].y);
      acc[11].x = fmaf(c2.w, xu.x, acc[11].x); acc[11].y = fmaf(c2.w, xu.y, acc[11].y);
      acc[12].x = fmaf(c3.x, xu.x, acc[12].x); acc[12].y = fmaf(c3.x, xu.y, acc[12].y);
      acc[13].x = fmaf(c3.y, xu.x, acc[13].x); acc[13].y = fmaf(c3.y, xu.y, acc[13].y);
      acc[14].x = fmaf(c3.z, xu.x, acc[14].x); acc[14].y = fmaf(c3.z, xu.y, acc[14].y);
      acc[15].x = fmaf(c3.w, xu.x, acc[15].x); acc[15].y = fmaf(c3.w, xu.y, acc[15].y);
    }
  }
  float2* up = (float2*)Upart;
#pragma unroll
  for (int j = 0; j < 16; ++j) {
    int g = slice * 16 + j;
    up[((size_t)blockIdx.y * 64 + g) * 256 + n2] = acc[j];
  }
}

// ---------------- stacked-row fp32 GEMM: C[M,N] = [A0; extraRow] @ B + guard ----------------
// rows 0..R0-1 from A0, row R0 = extra (single row), rows > R0 zero. BM=32 BN=64 BK=16.
__global__ __launch_bounds__(256) void gemm_stack(const float* __restrict__ A0,
                                                  const float* __restrict__ extra,
                                                  const float* __restrict__ B,
                                                  float* __restrict__ C,
                                                  int M, int N, int K, int R0) {
  __shared__ float As[16][33];
  __shared__ float Bs[16][65];
  int tid = threadIdx.x;
  int tx = tid & 15;
  int ty = tid >> 4;
  int bm = blockIdx.x * 32;
  int bn = blockIdx.y * 64;

  int ar = tid >> 3;        // 0..31 : A row in tile
  int ac = (tid & 7) * 2;   // 0..14 : k offset (float2)
  int br = tid >> 4;        // 0..15 : B k row
  int bc = (tid & 15) * 4;  // B col offset (float4)

  float acc[2][4] = {};

  for (int k0 = 0; k0 < K; k0 += 16) {
    int row = bm + ar;
    float2 av = make_float2(0.f, 0.f);
    if (row < R0)       av = *(const float2*)(A0 + (size_t)row * K + k0 + ac);
    else if (row == R0) av = *(const float2*)(extra + k0 + ac);
    As[ac + 0][ar] = av.x;
    As[ac + 1][ar] = av.y;
    float4 bv = *(const float4*)(B + (size_t)(k0 + br) * N + bn + bc);
    Bs[br][bc + 0] = bv.x;
    Bs[br][bc + 1] = bv.y;
    Bs[br][bc + 2] = bv.z;
    Bs[br][bc + 3] = bv.w;
    __syncthreads();
#pragma unroll
    for (int kk = 0; kk < 16; ++kk) {
      float a0 = As[kk][ty * 2 + 0];
      float a1 = As[kk][ty * 2 + 1];
      float b0 = Bs[kk][tx * 4 + 0];
      float b1 = Bs[kk][tx * 4 + 1];
      float b2 = Bs[kk][tx * 4 + 2];
      float b3 = Bs[kk][tx * 4 + 3];
      acc[0][0] = fmaf(a0, b0, acc[0][0]); acc[0][1] = fmaf(a0, b1, acc[0][1]);
      acc[0][2] = fmaf(a0, b2, acc[0][2]); acc[0][3] = fmaf(a0, b3, acc[0][3]);
      acc[1][0] = fmaf(a1, b0, acc[1][0]); acc[1][1] = fmaf(a1, b1, acc[1][1]);
      acc[1][2] = fmaf(a1, b2, acc[1][2]); acc[1][3] = fmaf(a1, b3, acc[1][3]);
    }
    __syncthreads();
  }

#pragma unroll
  for (int i = 0; i < 2; ++i) {
    int m = bm + ty * 2 + i;
    if (m >= M) continue;
#pragma unroll
    for (int j = 0; j < 4; ++j) {
      C[(size_t)m * N + bn + tx * 4 + j] = acc[i][j];
    }
  }
}

// ---------------- fused head (reduces Upart inline) ----------------
// P layout: P[0:512] = Wc (512x256), P[512] = v1, P[513] = v2
__global__ __launch_bounds__(256) void head(const float* __restrict__ Upart,
                                            const float* __restrict__ P,
                                            const float* __restrict__ ng,
                                            const float* __restrict__ eh,
                                            const float* __restrict__ bc1,
                                            const float* __restrict__ Wc2,
                                            const float* __restrict__ bc2,
                                            float* __restrict__ out) {
  int g = blockIdx.x;
  int j = threadIdx.x;
  const float* Wc = P;
  const float* v1 = P + (size_t)512 * 256;
  const float* v2 = P + (size_t)513 * 256;
  __shared__ float p[512];
  float s0 = 0.f, s1 = 0.f;
  for (int c = 0; c < NCHUNK; ++c) {
    s0 += Upart[((size_t)c * 64 + g) * DIM + j];
    s1 += Upart[((size_t)c * 64 + g) * DIM + 256 + j];
  }
  p[j] = s0;
  p[j + 256] = s1;
  __syncthreads();
  float cg = ng[g] + eh[g];
  float acc = bc1[j] + cg * v1[j] + ng[g] * v2[j];
  for (int k = 0; k < 512; ++k) acc = fmaf(p[k], Wc[k * 256 + j], acc);
  float z = fmaxf(acc, 0.f);
  float part = z * Wc2[j];
  for (int off = 32; off > 0; off >>= 1) part += __shfl_down(part, off, 64);
  __shared__ float red[4];
  if ((j & 63) == 0) red[j >> 6] = part;
  __syncthreads();
  if (j == 0) {
    float tot = red[0] + red[1] + red[2] + red[3] + bc2[0];
    out[g] = 1.f / (1.f + expf(-tot));
  }
}

extern "C" void kernel_launch(void* const* d_in, const int* in_sizes, int n_in,
                              void* d_out, int out_size, void* d_ws, size_t ws_size,
                              hipStream_t stream) {
  const float* x    = (const float*)d_in[0];
  const int*   ei   = (const int*)d_in[1];
  const int*   batch= (const int*)d_in[2];
  const float* Wg1  = (const float*)d_in[3];
  const float* bg1  = (const float*)d_in[4];
  const float* Wg2  = (const float*)d_in[5];
  const float* bg2  = (const float*)d_in[6];
  const float* Wc1  = (const float*)d_in[7];
  const float* bc1  = (const float*)d_in[8];
  const float* Wc2  = (const float*)d_in[9];
  const float* bc2  = (const float*)d_in[10];
  float* out = (float*)d_out;

  int n_edges = in_sizes[1] / 2;
  int n_nodes = in_sizes[2];
  const int* srcI = ei;
  const int* dstI = ei + n_edges;

  char* ws = (char*)d_ws;
  size_t off = 0;
  auto alloc = [&](size_t bytes) { char* p = ws + off; off += (bytes + 255) & ~(size_t)255; return p; };
  float* wT    = (float*)alloc((size_t)N_NODES * 64 * sizeof(float));        // 5.12 MB
  float* cT    = (float*)alloc((size_t)N_NODES * 64 * sizeof(float));        // 5.12 MB
  float* Upart = (float*)alloc((size_t)NCHUNK * 64 * DIM * sizeof(float));   // 20.6 MB
  float* G1    = (float*)alloc((size_t)513 * 512 * sizeof(float));           // [Wg1;bg1]@Wg2
  float* P     = (float*)alloc((size_t)514 * 256 * sizeof(float));           // [G1;bg2]@Wc1
  float* ng    = (float*)alloc(NG * sizeof(float));
  float* eh    = (float*)alloc(NG * sizeof(float));
  int* counts  = (int*)alloc(N_NODES * sizeof(int));
  int* rowptr  = (int*)alloc((N_NODES + 1) * sizeof(int));
  int* cursor  = (int*)alloc(N_NODES * sizeof(int));
  int* edst    = (int*)alloc((size_t)n_edges * sizeof(int));

  // --- coefficient build ---
  node_init<<<(n_nodes + 3) / 4, 256, 0, stream>>>(batch, wT, counts, ng, eh, n_nodes);
  edge_pass<<<640, 256, 0, stream>>>(srcI, dstI, batch, wT, counts, eh, n_edges);

  // --- CSR by source ---
  scan_counts<<<1, SCAN_THREADS, 0, stream>>>(counts, rowptr, cursor, n_nodes);
  fill_csr<<<1250, 256, 0, stream>>>(srcI, dstI, cursor, edst, n_edges);

  // --- c coefficients + U = cT^T @ x (chunked; head reduces partials) ---
  compute_cT<<<(n_nodes + 3) / 4, 256, 0, stream>>>(wT, rowptr, edst, cT, n_nodes);
  ugemm<<<dim3(4, NCHUNK), 256, 0, stream>>>(x, cT, Upart);

  // --- weight precompute: G1 = [Wg1;bg1]@Wg2 ; P = [G1;bg2]@Wc1 ---
  gemm_stack<<<dim3(17, 8), 256, 0, stream>>>(Wg1, bg1, Wg2, G1, 513, 512, 512, 512);
  gemm_stack<<<dim3(17, 4), 256, 0, stream>>>(G1, bg2, Wc1, P, 514, 256, 512, 513);

  // --- head ---
  head<<<NG, 256, 0, stream>>>(Upart, P, ng, eh, bc1, Wc2, bc2, out);
}

// Round 9
// 323.193 us; speedup vs baseline: 1.0862x; 1.0862x over previous
//
#include <hip/hip_runtime.h>
#include <math.h>

constexpr int N_NODES = 20000;
constexpr int DIM = 512;       // NODE_DIM == HIDDEN
constexpr int NG = 64;
constexpr int KCH = 128;       // U-GEMM k-chunk
constexpr int NCHUNK = (N_NODES + KCH - 1) / KCH;  // 157 (last chunk kmax=32, %4==0)
constexpr int RSPLIT = 4;
constexpr int CPS = (NCHUNK + RSPLIT - 1) / RSPLIT; // 40
constexpr int SCAN_THREADS = 1024;
constexpr int SCAN_CHUNK = 20; // 1024*20 = 20480 >= 20000

// ---------------- misc ----------------
__device__ __forceinline__ int lower_bound_i(const int* __restrict__ a, int n, int v) {
  int lo = 0, hi = n;
  while (lo < hi) {
    int mid = (lo + hi) >> 1;
    if (a[mid] < v) lo = mid + 1; else hi = mid;
  }
  return lo;
}

// counts[j]=0 (grid-stride); block 0 also: ng[g] via binary search, eh[g]=0
__global__ __launch_bounds__(256) void node_init(const int* __restrict__ batch,
                                                 int* __restrict__ counts,
                                                 float* __restrict__ ng,
                                                 float* __restrict__ eh, int n_nodes) {
  int i = blockIdx.x * blockDim.x + threadIdx.x;
  int stride = gridDim.x * blockDim.x;
  for (; i < n_nodes; i += stride) counts[i] = 0;
  if (blockIdx.x == 0 && threadIdx.x < 64) {
    int gg = threadIdx.x;
    int s0 = lower_bound_i(batch, n_nodes, gg);
    int e0 = lower_bound_i(batch, n_nodes, gg + 1);
    ng[gg] = (float)(e0 - s0);
    eh[gg] = 0.f;
  }
}

// one int atomic per edge: counts[src]++ ; eh hist via LDS
__global__ __launch_bounds__(256) void count_pass(const int* __restrict__ srcI,
                                                  const int* __restrict__ dstI,
                                                  const int* __restrict__ batch,
                                                  int* __restrict__ counts,
                                                  float* __restrict__ eh, int n_edges) {
  __shared__ int hist[64];
  int t = threadIdx.x;
  if (t < 64) hist[t] = 0;
  __syncthreads();
  int i = blockIdx.x * 256 + t;
  int stride = gridDim.x * 256;
  for (; i < n_edges; i += stride) {
    int s = srcI[i];
    int b = batch[dstI[i]];
    atomicAdd(&counts[s], 1);
    atomicAdd(&hist[b], 1);
  }
  __syncthreads();
  if (t < 64 && hist[t] != 0) atomicAdd(&eh[t], (float)hist[t]);
}

// ---------------- CSR scan: coalesced via 80 KB LDS staging ----------------
__global__ __launch_bounds__(SCAN_THREADS) void scan_counts(const int* __restrict__ counts,
                                                            int* __restrict__ rowptr,
                                                            int* __restrict__ cursor, int n) {
  __shared__ int buf[N_NODES];  // 80 KB
  int t = threadIdx.x;
  for (int i = t; i < n; i += SCAN_THREADS) buf[i] = counts[i];
  __syncthreads();
  int lane = t & 63;
  int wave = t >> 6;  // 0..15
  int base = t * SCAN_CHUNK;
  int partial = 0;
#pragma unroll
  for (int j = 0; j < SCAN_CHUNK; ++j) {
    int idx = base + j;
    if (idx < n) partial += buf[idx];
  }
  int incl = partial;
  for (int off = 1; off < 64; off <<= 1) {
    int v = __shfl_up(incl, off, 64);
    if (lane >= off) incl += v;
  }
  __shared__ int wsum[16];
  if (lane == 63) wsum[wave] = incl;
  __syncthreads();
  if (wave == 0 && lane < 16) {
    int v = wsum[lane];
    int wincl = v;
    for (int off = 1; off < 16; off <<= 1) {
      int u = __shfl_up(wincl, off, 64);
      if (lane >= off) wincl += u;
    }
    wsum[lane] = wincl - v;  // exclusive wave offset
  }
  __syncthreads();
  int run = incl - partial + wsum[wave];  // exclusive prefix for this chunk
#pragma unroll
  for (int j = 0; j < SCAN_CHUNK; ++j) {
    int idx = base + j;
    if (idx < n) {
      int old = buf[idx];
      buf[idx] = run;
      run += old;
    }
  }
  __syncthreads();
  for (int i = t; i < n; i += SCAN_THREADS) {
    int v = buf[i];
    rowptr[i] = v;
    cursor[i] = v;
  }
  if (t == SCAN_THREADS - 1) rowptr[n] = run;  // last chunk -> total
}

__global__ void fill_csr(const int* __restrict__ srcI, const int* __restrict__ dstI,
                         int* __restrict__ cursor, int* __restrict__ edst, int n_edges) {
  int i = blockIdx.x * blockDim.x + threadIdx.x;
  int stride = gridDim.x * blockDim.x;
  for (; i < n_edges; i += stride) {
    int pos = atomicAdd(&cursor[srcI[i]], 1);
    edst[pos] = dstI[i];
  }
}

// ---------------- wT[j][g] = [batch_j==g] + sum_{d in N(j)} [batch_d==g] ----------------
// atomic-free: per-node wave gather over neighbor batch values (x4 unrolled).
__global__ __launch_bounds__(256) void build_wT(const int* __restrict__ batch,
                                                const int* __restrict__ rowptr,
                                                const int* __restrict__ edst,
                                                float* __restrict__ wT, int n_nodes) {
  int node = blockIdx.x * 4 + (threadIdx.x >> 6);
  int g = threadIdx.x & 63;
  if (node >= n_nodes) return;
  int acc = (batch[node] == g) ? 1 : 0;
  int beg = rowptr[node];
  int end = rowptr[node + 1];
  int i = beg;
  for (; i + 3 < end; i += 4) {
    int d0 = edst[i], d1 = edst[i + 1], d2 = edst[i + 2], d3 = edst[i + 3];
    int b0 = batch[d0], b1 = batch[d1], b2 = batch[d2], b3 = batch[d3];
    acc += (b0 == g) + (b1 == g) + (b2 == g) + (b3 == g);
  }
  for (; i < end; ++i) acc += (batch[edst[i]] == g) ? 1 : 0;
  wT[(size_t)node * 64 + g] = (float)acc;
}

// ---------------- cT[k][g] = wT[k][g] + sum_{e:src=k} wT[dst(e)][g] (x4 unrolled) ----------------
__global__ __launch_bounds__(256) void compute_cT(const float* __restrict__ wT,
                                                  const int* __restrict__ rowptr,
                                                  const int* __restrict__ edst,
                                                  float* __restrict__ cT, int n_nodes) {
  int node = blockIdx.x * 4 + (threadIdx.x >> 6);
  int g = threadIdx.x & 63;
  if (node >= n_nodes) return;
  float acc = wT[(size_t)node * 64 + g];
  int beg = rowptr[node];
  int end = rowptr[node + 1];
  int i = beg;
  for (; i + 3 < end; i += 4) {
    int d0 = edst[i], d1 = edst[i + 1], d2 = edst[i + 2], d3 = edst[i + 3];
    acc += wT[(size_t)d0 * 64 + g] + wT[(size_t)d1 * 64 + g] +
           wT[(size_t)d2 * 64 + g] + wT[(size_t)d3 * 64 + g];
  }
  for (; i < end; ++i) acc += wT[(size_t)edst[i] * 64 + g];
  cT[(size_t)node * 64 + g] = acc;
}

// ---------------- U-GEMM: Upart[c][g][n] = sum_{k in chunk c} cT[k][g]*x[k][n] ----------------
__global__ __launch_bounds__(256) void ugemm(const float* __restrict__ x,
                                             const float* __restrict__ cT,
                                             float* __restrict__ Upart) {
  __shared__ float sc[KCH][64];  // 32 KB
  int t = threadIdx.x;
  int k0 = blockIdx.y * KCH;
  int kmax = (N_NODES - k0) < KCH ? (N_NODES - k0) : KCH;  // 128 or 32; %4==0
  {
    const float4* src = (const float4*)(cT + (size_t)k0 * 64);
    float4* dst = (float4*)(&sc[0][0]);
    int limit4 = kmax * 16;
    for (int i = t; i < limit4; i += 256) dst[i] = src[i];
  }
  __syncthreads();
  int lane = t & 63;
  int slice = t >> 6;                 // g-range [slice*16, slice*16+16)
  int n2 = blockIdx.x * 64 + lane;    // float2 col 0..255
  const float2* x2 = (const float2*)x;
  float2 acc[16];
#pragma unroll
  for (int j = 0; j < 16; ++j) acc[j] = make_float2(0.f, 0.f);
  for (int kk = 0; kk < kmax; kk += 4) {
    float2 xv[4];
#pragma unroll
    for (int u = 0; u < 4; ++u)
      xv[u] = x2[(size_t)(k0 + kk + u) * 256 + n2];
#pragma unroll
    for (int u = 0; u < 4; ++u) {
      const float4* cp = (const float4*)&sc[kk + u][slice * 16];
      float4 c0 = cp[0], c1 = cp[1], c2 = cp[2], c3 = cp[3];
      float2 xu = xv[u];
      acc[0].x  = fmaf(c0.x, xu.x, acc[0].x);  acc[0].y  = fmaf(c0.x, xu.y, acc[0].y);
      acc[1].x  = fmaf(c0.y, xu.x, acc[1].x);  acc[1].y  = fmaf(c0.y, xu.y, acc[1].y);
      acc[2].x  = fmaf(c0.z, xu.x, acc[2].x);  acc[2].y  = fmaf(c0.z, xu.y, acc[2].y);
      acc[3].x  = fmaf(c0.w, xu.x, acc[3].x);  acc[3].y  = fmaf(c0.w, xu.y, acc[3].y);
      acc[4].x  = fmaf(c1.x, xu.x, acc[4].x);  acc[4].y  = fmaf(c1.x, xu.y, acc[4].y);
      acc[5].x  = fmaf(c1.y, xu.x, acc[5].x);  acc[5].y  = fmaf(c1.y, xu.y, acc[5].y);
      acc[6].x  = fmaf(c1.z, xu.x, acc[6].x);  acc[6].y  = fmaf(c1.z, xu.y, acc[6].y);
      acc[7].x  = fmaf(c1.w, xu.x, acc[7].x);  acc[7].y  = fmaf(c1.w, xu.y, acc[7].y);
      acc[8].x  = fmaf(c2.x, xu.x, acc[8].x);  acc[8].y  = fmaf(c2.x, xu.y, acc[8].y);
      acc[9].x  = fmaf(c2.y, xu.x, acc[9].x);  acc[9].y  = fmaf(c2.y, xu.y, acc[9].y);
      acc[10].x = fmaf(c2.z, xu.x, acc[10].x); acc[10].y = fmaf(c2.z, xu.y, acc[10].y);
      acc[11].x = fmaf(c2.w, xu.x, acc[11].x); acc[11].y = fmaf(c2.w, xu.y, acc[11].y);
      acc[12].x = fmaf(c3.x, xu.x, acc[12].x); acc[12].y = fmaf(c3.x, xu.y, acc[12].y);
      acc[13].x = fmaf(c3.y, xu.x, acc[13].x); acc[13].y = fmaf(c3.y, xu.y, acc[13].y);
      acc[14].x = fmaf(c3.z, xu.x, acc[14].x); acc[14].y = fmaf(c3.z, xu.y, acc[14].y);
      acc[15].x = fmaf(c3.w, xu.x, acc[15].x); acc[15].y = fmaf(c3.w, xu.y, acc[15].y);
    }
  }
  float2* up = (float2*)Upart;
#pragma unroll
  for (int j = 0; j < 16; ++j) {
    int g = slice * 16 + j;
    up[((size_t)blockIdx.y * 64 + g) * 256 + n2] = acc[j];
  }
}

// ---------------- Upart reduce: Ured[s][g][n] = sum_{c in split s} Upart[c][g][n] ----------------
__global__ __launch_bounds__(128) void reduce_U(const float* __restrict__ Upart,
                                                float* __restrict__ Ured) {
  int g = blockIdx.x;   // 0..63
  int s = blockIdx.y;   // 0..RSPLIT-1
  int t = threadIdx.x;  // 0..127 float4 over 512
  int c0 = s * CPS;
  int c1 = (c0 + CPS < NCHUNK) ? c0 + CPS : NCHUNK;
  const float4* up = (const float4*)Upart;
  float4 acc = make_float4(0.f, 0.f, 0.f, 0.f);
  for (int c = c0; c < c1; ++c) {
    float4 v = up[((size_t)c * 64 + g) * 128 + t];
    acc.x += v.x; acc.y += v.y; acc.z += v.z; acc.w += v.w;
  }
  ((float4*)Ured)[((size_t)s * 64 + g) * 128 + t] = acc;
}

// ---------------- stacked-row fp32 GEMM: C[M,N] = [A0; extraRow] @ B ----------------
__global__ __launch_bounds__(256) void gemm_stack(const float* __restrict__ A0,
                                                  const float* __restrict__ extra,
                                                  const float* __restrict__ B,
                                                  float* __restrict__ C,
                                                  int M, int N, int K, int R0) {
  __shared__ float As[16][33];
  __shared__ float Bs[16][65];
  int tid = threadIdx.x;
  int tx = tid & 15;
  int ty = tid >> 4;
  int bm = blockIdx.x * 32;
  int bn = blockIdx.y * 64;

  int ar = tid >> 3;        // 0..31 : A row in tile
  int ac = (tid & 7) * 2;   // 0..14 : k offset (float2)
  int br = tid >> 4;        // 0..15 : B k row
  int bc = (tid & 15) * 4;  // B col offset (float4)

  float acc[2][4] = {};

  for (int k0 = 0; k0 < K; k0 += 16) {
    int row = bm + ar;
    float2 av = make_float2(0.f, 0.f);
    if (row < R0)       av = *(const float2*)(A0 + (size_t)row * K + k0 + ac);
    else if (row == R0) av = *(const float2*)(extra + k0 + ac);
    As[ac + 0][ar] = av.x;
    As[ac + 1][ar] = av.y;
    float4 bv = *(const float4*)(B + (size_t)(k0 + br) * N + bn + bc);
    Bs[br][bc + 0] = bv.x;
    Bs[br][bc + 1] = bv.y;
    Bs[br][bc + 2] = bv.z;
    Bs[br][bc + 3] = bv.w;
    __syncthreads();
#pragma unroll
    for (int kk = 0; kk < 16; ++kk) {
      float a0 = As[kk][ty * 2 + 0];
      float a1 = As[kk][ty * 2 + 1];
      float b0 = Bs[kk][tx * 4 + 0];
      float b1 = Bs[kk][tx * 4 + 1];
      float b2 = Bs[kk][tx * 4 + 2];
      float b3 = Bs[kk][tx * 4 + 3];
      acc[0][0] = fmaf(a0, b0, acc[0][0]); acc[0][1] = fmaf(a0, b1, acc[0][1]);
      acc[0][2] = fmaf(a0, b2, acc[0][2]); acc[0][3] = fmaf(a0, b3, acc[0][3]);
      acc[1][0] = fmaf(a1, b0, acc[1][0]); acc[1][1] = fmaf(a1, b1, acc[1][1]);
      acc[1][2] = fmaf(a1, b2, acc[1][2]); acc[1][3] = fmaf(a1, b3, acc[1][3]);
    }
    __syncthreads();
  }

#pragma unroll
  for (int i = 0; i < 2; ++i) {
    int m = bm + ty * 2 + i;
    if (m >= M) continue;
#pragma unroll
    for (int j = 0; j < 4; ++j) {
      C[(size_t)m * N + bn + tx * 4 + j] = acc[i][j];
    }
  }
}

// ---------------- fused head ----------------
// P[0:512] = Wc, P[512] = v1 ; Q[512] = v2
__global__ __launch_bounds__(256) void head(const float* __restrict__ Ured,
                                            const float* __restrict__ P,
                                            const float* __restrict__ Q,
                                            const float* __restrict__ ng,
                                            const float* __restrict__ eh,
                                            const float* __restrict__ bc1,
                                            const float* __restrict__ Wc2,
                                            const float* __restrict__ bc2,
                                            float* __restrict__ out) {
  int g = blockIdx.x;
  int j = threadIdx.x;
  const float* Wc = P;
  const float* v1 = P + (size_t)512 * 256;
  const float* v2 = Q + (size_t)512 * 256;
  __shared__ float p[512];
  float s0 = 0.f, s1 = 0.f;
#pragma unroll
  for (int s = 0; s < RSPLIT; ++s) {
    s0 += Ured[((size_t)s * 64 + g) * DIM + j];
    s1 += Ured[((size_t)s * 64 + g) * DIM + 256 + j];
  }
  p[j] = s0;
  p[j + 256] = s1;
  __syncthreads();
  float cg = ng[g] + eh[g];
  float acc = bc1[j] + cg * v1[j] + ng[g] * v2[j];
  for (int k = 0; k < 512; ++k) acc = fmaf(p[k], Wc[k * 256 + j], acc);
  float z = fmaxf(acc, 0.f);
  float part = z * Wc2[j];
  for (int off = 32; off > 0; off >>= 1) part += __shfl_down(part, off, 64);
  __shared__ float red[4];
  if ((j & 63) == 0) red[j >> 6] = part;
  __syncthreads();
  if (j == 0) {
    float tot = red[0] + red[1] + red[2] + red[3] + bc2[0];
    out[g] = 1.f / (1.f + expf(-tot));
  }
}

extern "C" void kernel_launch(void* const* d_in, const int* in_sizes, int n_in,
                              void* d_out, int out_size, void* d_ws, size_t ws_size,
                              hipStream_t stream) {
  const float* x    = (const float*)d_in[0];
  const int*   ei   = (const int*)d_in[1];
  const int*   batch= (const int*)d_in[2];
  const float* Wg1  = (const float*)d_in[3];
  const float* bg1  = (const float*)d_in[4];
  const float* Wg2  = (const float*)d_in[5];
  const float* bg2  = (const float*)d_in[6];
  const float* Wc1  = (const float*)d_in[7];
  const float* bc1  = (const float*)d_in[8];
  const float* Wc2  = (const float*)d_in[9];
  const float* bc2  = (const float*)d_in[10];
  float* out = (float*)d_out;

  int n_edges = in_sizes[1] / 2;
  int n_nodes = in_sizes[2];
  const int* srcI = ei;
  const int* dstI = ei + n_edges;

  char* ws = (char*)d_ws;
  size_t off = 0;
  auto alloc = [&](size_t bytes) { char* p = ws + off; off += (bytes + 255) & ~(size_t)255; return p; };
  float* wT    = (float*)alloc((size_t)N_NODES * 64 * sizeof(float));        // 5.12 MB
  float* cT    = (float*)alloc((size_t)N_NODES * 64 * sizeof(float));        // 5.12 MB
  float* Upart = (float*)alloc((size_t)NCHUNK * 64 * DIM * sizeof(float));   // 20.6 MB
  float* Ured  = (float*)alloc((size_t)RSPLIT * 64 * DIM * sizeof(float));   // 512 KB
  float* Q     = (float*)alloc((size_t)513 * 256 * sizeof(float));           // [Wg2;bg2]@Wc1
  float* P     = (float*)alloc((size_t)513 * 256 * sizeof(float));           // [Wg1;bg1]@Q0
  float* ng    = (float*)alloc(NG * sizeof(float));
  float* eh    = (float*)alloc(NG * sizeof(float));
  int* counts  = (int*)alloc(N_NODES * sizeof(int));
  int* rowptr  = (int*)alloc((N_NODES + 1) * sizeof(int));
  int* cursor  = (int*)alloc(N_NODES * sizeof(int));
  int* edst    = (int*)alloc((size_t)n_edges * sizeof(int));

  // --- degree counts + per-graph edge hist (1 int atomic/edge) ---
  node_init<<<80, 256, 0, stream>>>(batch, counts, ng, eh, n_nodes);
  count_pass<<<1250, 256, 0, stream>>>(srcI, dstI, batch, counts, eh, n_edges);

  // --- CSR by source ---
  scan_counts<<<1, SCAN_THREADS, 0, stream>>>(counts, rowptr, cursor, n_nodes);
  fill_csr<<<1250, 256, 0, stream>>>(srcI, dstI, cursor, edst, n_edges);

  // --- coefficients (atomic-free gathers) + U = cT^T @ x ---
  build_wT<<<(n_nodes + 3) / 4, 256, 0, stream>>>(batch, rowptr, edst, wT, n_nodes);
  compute_cT<<<(n_nodes + 3) / 4, 256, 0, stream>>>(wT, rowptr, edst, cT, n_nodes);
  ugemm<<<dim3(4, NCHUNK), 256, 0, stream>>>(x, cT, Upart);
  reduce_U<<<dim3(64, RSPLIT), 128, 0, stream>>>(Upart, Ured);

  // --- weight precompute: Q = [Wg2;bg2]@Wc1 ; P = [Wg1;bg1]@Q[0:512] ---
  gemm_stack<<<dim3(17, 4), 256, 0, stream>>>(Wg2, bg2, Wc1, Q, 513, 256, 512, 512);
  gemm_stack<<<dim3(17, 4), 256, 0, stream>>>(Wg1, bg1, Q, P, 513, 256, 512, 512);

  // --- head ---
  head<<<NG, 256, 0, stream>>>(Ured, P, Q, ng, eh, bc1, Wc2, bc2, out);
}

// Round 10
// 311.277 us; speedup vs baseline: 1.1278x; 1.0383x over previous
//
#include <hip/hip_runtime.h>
#include <math.h>

constexpr int N_NODES = 20000;
constexpr int DIM = 512;       // NODE_DIM == HIDDEN
constexpr int NG = 64;
constexpr int KCH = 128;       // U-GEMM k-chunk
constexpr int NCHUNK = (N_NODES + KCH - 1) / KCH;  // 157 (last chunk kmax=32, %4==0)
constexpr int RSPLIT = 4;
constexpr int CPS = (NCHUNK + RSPLIT - 1) / RSPLIT; // 40
constexpr int SCAN_THREADS = 1024;
constexpr int SCAN_CHUNK = 20; // 1024*20 = 20480 >= 20000
constexpr int CGS = 32;        // cgpad stride (floats) -> 128B, one cacheline per graph

// ---------------- misc ----------------
__device__ __forceinline__ int lower_bound_i(const int* __restrict__ a, int n, int v) {
  int lo = 0, hi = n;
  while (lo < hi) {
    int mid = (lo + hi) >> 1;
    if (a[mid] < v) lo = mid + 1; else hi = mid;
  }
  return lo;
}

// counts[j]=0 (grid-stride); block 0 also: ng[g] via binary search, cgpad zero
__global__ __launch_bounds__(256) void node_init(const int* __restrict__ batch,
                                                 int* __restrict__ counts,
                                                 float* __restrict__ ng,
                                                 float* __restrict__ cgpad, int n_nodes) {
  int i = blockIdx.x * blockDim.x + threadIdx.x;
  int stride = gridDim.x * blockDim.x;
  for (; i < n_nodes; i += stride) counts[i] = 0;
  if (blockIdx.x == 0 && threadIdx.x < 64) {
    int gg = threadIdx.x;
    int s0 = lower_bound_i(batch, n_nodes, gg);
    int e0 = lower_bound_i(batch, n_nodes, gg + 1);
    ng[gg] = (float)(e0 - s0);
    cgpad[gg * CGS] = 0.f;
  }
}

// pure degree count: one int atomic per edge, nothing else
__global__ __launch_bounds__(256) void count_pass(const int* __restrict__ srcI,
                                                  int* __restrict__ counts, int n_edges) {
  int i = blockIdx.x * 256 + threadIdx.x;
  if (i < n_edges) atomicAdd(&counts[srcI[i]], 1);
}

// ---------------- CSR scan: coalesced via 80 KB LDS staging ----------------
__global__ __launch_bounds__(SCAN_THREADS) void scan_counts(const int* __restrict__ counts,
                                                            int* __restrict__ rowptr,
                                                            int* __restrict__ cursor, int n) {
  __shared__ int buf[N_NODES];  // 80 KB
  int t = threadIdx.x;
  for (int i = t; i < n; i += SCAN_THREADS) buf[i] = counts[i];
  __syncthreads();
  int lane = t & 63;
  int wave = t >> 6;  // 0..15
  int base = t * SCAN_CHUNK;
  int partial = 0;
#pragma unroll
  for (int j = 0; j < SCAN_CHUNK; ++j) {
    int idx = base + j;
    if (idx < n) partial += buf[idx];
  }
  int incl = partial;
  for (int off = 1; off < 64; off <<= 1) {
    int v = __shfl_up(incl, off, 64);
    if (lane >= off) incl += v;
  }
  __shared__ int wsum[16];
  if (lane == 63) wsum[wave] = incl;
  __syncthreads();
  if (wave == 0 && lane < 16) {
    int v = wsum[lane];
    int wincl = v;
    for (int off = 1; off < 16; off <<= 1) {
      int u = __shfl_up(wincl, off, 64);
      if (lane >= off) wincl += u;
    }
    wsum[lane] = wincl - v;  // exclusive wave offset
  }
  __syncthreads();
  int run = incl - partial + wsum[wave];  // exclusive prefix for this chunk
#pragma unroll
  for (int j = 0; j < SCAN_CHUNK; ++j) {
    int idx = base + j;
    if (idx < n) {
      int old = buf[idx];
      buf[idx] = run;
      run += old;
    }
  }
  __syncthreads();
  for (int i = t; i < n; i += SCAN_THREADS) {
    int v = buf[i];
    rowptr[i] = v;
    cursor[i] = v;
  }
  if (t == SCAN_THREADS - 1) rowptr[n] = run;  // last chunk -> total
}

__global__ void fill_csr(const int* __restrict__ srcI, const int* __restrict__ dstI,
                         int* __restrict__ cursor, int* __restrict__ edst, int n_edges) {
  int i = blockIdx.x * blockDim.x + threadIdx.x;
  if (i < n_edges) {
    int pos = atomicAdd(&cursor[srcI[i]], 1);
    edst[pos] = dstI[i];
  }
}

// ---------------- wT[j][g] = [batch_j==g] + sum_{d in N(j)} [batch_d==g] ----------------
__global__ __launch_bounds__(256) void build_wT(const int* __restrict__ batch,
                                                const int* __restrict__ rowptr,
                                                const int* __restrict__ edst,
                                                float* __restrict__ wT, int n_nodes) {
  int node = blockIdx.x * 4 + (threadIdx.x >> 6);
  int g = threadIdx.x & 63;
  if (node >= n_nodes) return;
  int acc = (batch[node] == g) ? 1 : 0;
  int beg = rowptr[node];
  int end = rowptr[node + 1];
  int i = beg;
  for (; i + 3 < end; i += 4) {
    int d0 = edst[i], d1 = edst[i + 1], d2 = edst[i + 2], d3 = edst[i + 3];
    int b0 = batch[d0], b1 = batch[d1], b2 = batch[d2], b3 = batch[d3];
    acc += (b0 == g) + (b1 == g) + (b2 == g) + (b3 == g);
  }
  for (; i < end; ++i) acc += (batch[edst[i]] == g) ? 1 : 0;
  wT[(size_t)node * 64 + g] = (float)acc;
}

// ---------------- cg[g] = colsum(wT)[g] = n_g + (#edges into graph g) ----------------
// 80 blocks x (4 waves x 64 lanes); per-block LDS reduce; padded atomics (1 line/graph)
__global__ __launch_bounds__(256) void colsum_wT(const float* __restrict__ wT,
                                                 float* __restrict__ cgpad, int n_nodes) {
  int wave = threadIdx.x >> 6;
  int g = threadIdx.x & 63;
  float acc = 0.f;
  for (int node = blockIdx.x * 4 + wave; node < n_nodes; node += gridDim.x * 4)
    acc += wT[(size_t)node * 64 + g];
  __shared__ float s[4][64];
  s[wave][g] = acc;
  __syncthreads();
  if (wave == 0) {
    float v = s[0][g] + s[1][g] + s[2][g] + s[3][g];
    atomicAdd(&cgpad[g * CGS], v);
  }
}

// ---------------- cT[k][g] = wT[k][g] + sum_{e:src=k} wT[dst(e)][g] (x4 unrolled) ----------------
__global__ __launch_bounds__(256) void compute_cT(const float* __restrict__ wT,
                                                  const int* __restrict__ rowptr,
                                                  const int* __restrict__ edst,
                                                  float* __restrict__ cT, int n_nodes) {
  int node = blockIdx.x * 4 + (threadIdx.x >> 6);
  int g = threadIdx.x & 63;
  if (node >= n_nodes) return;
  float acc = wT[(size_t)node * 64 + g];
  int beg = rowptr[node];
  int end = rowptr[node + 1];
  int i = beg;
  for (; i + 3 < end; i += 4) {
    int d0 = edst[i], d1 = edst[i + 1], d2 = edst[i + 2], d3 = edst[i + 3];
    acc += wT[(size_t)d0 * 64 + g] + wT[(size_t)d1 * 64 + g] +
           wT[(size_t)d2 * 64 + g] + wT[(size_t)d3 * 64 + g];
  }
  for (; i < end; ++i) acc += wT[(size_t)edst[i] * 64 + g];
  cT[(size_t)node * 64 + g] = acc;
}

// ---------------- U-GEMM: Upart[c][g][n] = sum_{k in chunk c} cT[k][g]*x[k][n] ----------------
__global__ __launch_bounds__(256) void ugemm(const float* __restrict__ x,
                                             const float* __restrict__ cT,
                                             float* __restrict__ Upart) {
  __shared__ float sc[KCH][64];  // 32 KB
  int t = threadIdx.x;
  int k0 = blockIdx.y * KCH;
  int kmax = (N_NODES - k0) < KCH ? (N_NODES - k0) : KCH;  // 128 or 32; %4==0
  {
    const float4* src = (const float4*)(cT + (size_t)k0 * 64);
    float4* dst = (float4*)(&sc[0][0]);
    int limit4 = kmax * 16;
    for (int i = t; i < limit4; i += 256) dst[i] = src[i];
  }
  __syncthreads();
  int lane = t & 63;
  int slice = t >> 6;                 // g-range [slice*16, slice*16+16)
  int n2 = blockIdx.x * 64 + lane;    // float2 col 0..255
  const float2* x2 = (const float2*)x;
  float2 acc[16];
#pragma unroll
  for (int j = 0; j < 16; ++j) acc[j] = make_float2(0.f, 0.f);
  for (int kk = 0; kk < kmax; kk += 4) {
    float2 xv[4];
#pragma unroll
    for (int u = 0; u < 4; ++u)
      xv[u] = x2[(size_t)(k0 + kk + u) * 256 + n2];
#pragma unroll
    for (int u = 0; u < 4; ++u) {
      const float4* cp = (const float4*)&sc[kk + u][slice * 16];
      float4 c0 = cp[0], c1 = cp[1], c2 = cp[2], c3 = cp[3];
      float2 xu = xv[u];
      acc[0].x  = fmaf(c0.x, xu.x, acc[0].x);  acc[0].y  = fmaf(c0.x, xu.y, acc[0].y);
      acc[1].x  = fmaf(c0.y, xu.x, acc[1].x);  acc[1].y  = fmaf(c0.y, xu.y, acc[1].y);
      acc[2].x  = fmaf(c0.z, xu.x, acc[2].x);  acc[2].y  = fmaf(c0.z, xu.y, acc[2].y);
      acc[3].x  = fmaf(c0.w, xu.x, acc[3].x);  acc[3].y  = fmaf(c0.w, xu.y, acc[3].y);
      acc[4].x  = fmaf(c1.x, xu.x, acc[4].x);  acc[4].y  = fmaf(c1.x, xu.y, acc[4].y);
      acc[5].x  = fmaf(c1.y, xu.x, acc[5].x);  acc[5].y  = fmaf(c1.y, xu.y, acc[5].y);
      acc[6].x  = fmaf(c1.z, xu.x, acc[6].x);  acc[6].y  = fmaf(c1.z, xu.y, acc[6].y);
      acc[7].x  = fmaf(c1.w, xu.x, acc[7].x);  acc[7].y  = fmaf(c1.w, xu.y, acc[7].y);
      acc[8].x  = fmaf(c2.x, xu.x, acc[8].x);  acc[8].y  = fmaf(c2.x, xu.y, acc[8].y);
      acc[9].x  = fmaf(c2.y, xu.x, acc[9].x);  acc[9].y  = fmaf(c2.y, xu.y, acc[9].y);
      acc[10].x = fmaf(c2.z, xu.x, acc[10].x); acc[10].y = fmaf(c2.z, xu.y, acc[10].y);
      acc[11].x = fmaf(c2.w, xu.x, acc[11].x); acc[11].y = fmaf(c2.w, xu.y, acc[11].y);
      acc[12].x = fmaf(c3.x, xu.x, acc[12].x); acc[12].y = fmaf(c3.x, xu.y, acc[12].y);
      acc[13].x = fmaf(c3.y, xu.x, acc[13].x); acc[13].y = fmaf(c3.y, xu.y, acc[13].y);
      acc[14].x = fmaf(c3.z, xu.x, acc[14].x); acc[14].y = fmaf(c3.z, xu.y, acc[14].y);
      acc[15].x = fmaf(c3.w, xu.x, acc[15].x); acc[15].y = fmaf(c3.w, xu.y, acc[15].y);
    }
  }
  float2* up = (float2*)Upart;
#pragma unroll
  for (int j = 0; j < 16; ++j) {
    int g = slice * 16 + j;
    up[((size_t)blockIdx.y * 64 + g) * 256 + n2] = acc[j];
  }
}

// ---------------- Upart reduce: Ured[s][g][n] = sum_{c in split s} Upart[c][g][n] ----------------
__global__ __launch_bounds__(128) void reduce_U(const float* __restrict__ Upart,
                                                float* __restrict__ Ured) {
  int g = blockIdx.x;   // 0..63
  int s = blockIdx.y;   // 0..RSPLIT-1
  int t = threadIdx.x;  // 0..127 float4 over 512
  int c0 = s * CPS;
  int c1 = (c0 + CPS < NCHUNK) ? c0 + CPS : NCHUNK;
  const float4* up = (const float4*)Upart;
  float4 acc = make_float4(0.f, 0.f, 0.f, 0.f);
  for (int c = c0; c < c1; ++c) {
    float4 v = up[((size_t)c * 64 + g) * 128 + t];
    acc.x += v.x; acc.y += v.y; acc.z += v.z; acc.w += v.w;
  }
  ((float4*)Ured)[((size_t)s * 64 + g) * 128 + t] = acc;
}

// ---------------- stacked-row fp32 GEMM: C[M,N] = [A0; extraRow] @ B ----------------
__global__ __launch_bounds__(256) void gemm_stack(const float* __restrict__ A0,
                                                  const float* __restrict__ extra,
                                                  const float* __restrict__ B,
                                                  float* __restrict__ C,
                                                  int M, int N, int K, int R0) {
  __shared__ float As[16][33];
  __shared__ float Bs[16][65];
  int tid = threadIdx.x;
  int tx = tid & 15;
  int ty = tid >> 4;
  int bm = blockIdx.x * 32;
  int bn = blockIdx.y * 64;

  int ar = tid >> 3;        // 0..31 : A row in tile
  int ac = (tid & 7) * 2;   // 0..14 : k offset (float2)
  int br = tid >> 4;        // 0..15 : B k row
  int bc = (tid & 15) * 4;  // B col offset (float4)

  float acc[2][4] = {};

  for (int k0 = 0; k0 < K; k0 += 16) {
    int row = bm + ar;
    float2 av = make_float2(0.f, 0.f);
    if (row < R0)       av = *(const float2*)(A0 + (size_t)row * K + k0 + ac);
    else if (row == R0) av = *(const float2*)(extra + k0 + ac);
    As[ac + 0][ar] = av.x;
    As[ac + 1][ar] = av.y;
    float4 bv = *(const float4*)(B + (size_t)(k0 + br) * N + bn + bc);
    Bs[br][bc + 0] = bv.x;
    Bs[br][bc + 1] = bv.y;
    Bs[br][bc + 2] = bv.z;
    Bs[br][bc + 3] = bv.w;
    __syncthreads();
#pragma unroll
    for (int kk = 0; kk < 16; ++kk) {
      float a0 = As[kk][ty * 2 + 0];
      float a1 = As[kk][ty * 2 + 1];
      float b0 = Bs[kk][tx * 4 + 0];
      float b1 = Bs[kk][tx * 4 + 1];
      float b2 = Bs[kk][tx * 4 + 2];
      float b3 = Bs[kk][tx * 4 + 3];
      acc[0][0] = fmaf(a0, b0, acc[0][0]); acc[0][1] = fmaf(a0, b1, acc[0][1]);
      acc[0][2] = fmaf(a0, b2, acc[0][2]); acc[0][3] = fmaf(a0, b3, acc[0][3]);
      acc[1][0] = fmaf(a1, b0, acc[1][0]); acc[1][1] = fmaf(a1, b1, acc[1][1]);
      acc[1][2] = fmaf(a1, b2, acc[1][2]); acc[1][3] = fmaf(a1, b3, acc[1][3]);
    }
    __syncthreads();
  }

#pragma unroll
  for (int i = 0; i < 2; ++i) {
    int m = bm + ty * 2 + i;
    if (m >= M) continue;
#pragma unroll
    for (int j = 0; j < 4; ++j) {
      C[(size_t)m * N + bn + tx * 4 + j] = acc[i][j];
    }
  }
}

// ---------------- fused head ----------------
// P[0:512] = Wc, P[512] = v1 ; Q[512] = v2 ; cg from cgpad
__global__ __launch_bounds__(256) void head(const float* __restrict__ Ured,
                                            const float* __restrict__ P,
                                            const float* __restrict__ Q,
                                            const float* __restrict__ ng,
                                            const float* __restrict__ cgpad,
                                            const float* __restrict__ bc1,
                                            const float* __restrict__ Wc2,
                                            const float* __restrict__ bc2,
                                            float* __restrict__ out) {
  int g = blockIdx.x;
  int j = threadIdx.x;
  const float* Wc = P;
  const float* v1 = P + (size_t)512 * 256;
  const float* v2 = Q + (size_t)512 * 256;
  __shared__ float p[512];
  float s0 = 0.f, s1 = 0.f;
#pragma unroll
  for (int s = 0; s < RSPLIT; ++s) {
    s0 += Ured[((size_t)s * 64 + g) * DIM + j];
    s1 += Ured[((size_t)s * 64 + g) * DIM + 256 + j];
  }
  p[j] = s0;
  p[j + 256] = s1;
  __syncthreads();
  float cg = cgpad[g * CGS];
  float acc = bc1[j] + cg * v1[j] + ng[g] * v2[j];
  for (int k = 0; k < 512; ++k) acc = fmaf(p[k], Wc[k * 256 + j], acc);
  float z = fmaxf(acc, 0.f);
  float part = z * Wc2[j];
  for (int off = 32; off > 0; off >>= 1) part += __shfl_down(part, off, 64);
  __shared__ float red[4];
  if ((j & 63) == 0) red[j >> 6] = part;
  __syncthreads();
  if (j == 0) {
    float tot = red[0] + red[1] + red[2] + red[3] + bc2[0];
    out[g] = 1.f / (1.f + expf(-tot));
  }
}

extern "C" void kernel_launch(void* const* d_in, const int* in_sizes, int n_in,
                              void* d_out, int out_size, void* d_ws, size_t ws_size,
                              hipStream_t stream) {
  const float* x    = (const float*)d_in[0];
  const int*   ei   = (const int*)d_in[1];
  const int*   batch= (const int*)d_in[2];
  const float* Wg1  = (const float*)d_in[3];
  const float* bg1  = (const float*)d_in[4];
  const float* Wg2  = (const float*)d_in[5];
  const float* bg2  = (const float*)d_in[6];
  const float* Wc1  = (const float*)d_in[7];
  const float* bc1  = (const float*)d_in[8];
  const float* Wc2  = (const float*)d_in[9];
  const float* bc2  = (const float*)d_in[10];
  float* out = (float*)d_out;

  int n_edges = in_sizes[1] / 2;
  int n_nodes = in_sizes[2];
  const int* srcI = ei;
  const int* dstI = ei + n_edges;

  char* ws = (char*)d_ws;
  size_t off = 0;
  auto alloc = [&](size_t bytes) { char* p = ws + off; off += (bytes + 255) & ~(size_t)255; return p; };
  float* wT    = (float*)alloc((size_t)N_NODES * 64 * sizeof(float));        // 5.12 MB
  float* cT    = (float*)alloc((size_t)N_NODES * 64 * sizeof(float));        // 5.12 MB
  float* Upart = (float*)alloc((size_t)NCHUNK * 64 * DIM * sizeof(float));   // 20.6 MB
  float* Ured  = (float*)alloc((size_t)RSPLIT * 64 * DIM * sizeof(float));   // 512 KB
  float* Q     = (float*)alloc((size_t)513 * 256 * sizeof(float));           // [Wg2;bg2]@Wc1
  float* P     = (float*)alloc((size_t)513 * 256 * sizeof(float));           // [Wg1;bg1]@Q0
  float* ng    = (float*)alloc(NG * sizeof(float));
  float* cgpad = (float*)alloc(NG * CGS * sizeof(float));
  int* counts  = (int*)alloc(N_NODES * sizeof(int));
  int* rowptr  = (int*)alloc((N_NODES + 1) * sizeof(int));
  int* cursor  = (int*)alloc(N_NODES * sizeof(int));
  int* edst    = (int*)alloc((size_t)n_edges * sizeof(int));

  // --- degree counts (1 int atomic/edge, nothing else) ---
  node_init<<<80, 256, 0, stream>>>(batch, counts, ng, cgpad, n_nodes);
  count_pass<<<(n_edges + 255) / 256, 256, 0, stream>>>(srcI, counts, n_edges);

  // --- CSR by source ---
  scan_counts<<<1, SCAN_THREADS, 0, stream>>>(counts, rowptr, cursor, n_nodes);
  fill_csr<<<(n_edges + 255) / 256, 256, 0, stream>>>(srcI, dstI, cursor, edst, n_edges);

  // --- coefficients (atomic-free gathers) + cg colsum + U = cT^T @ x ---
  build_wT<<<(n_nodes + 3) / 4, 256, 0, stream>>>(batch, rowptr, edst, wT, n_nodes);
  colsum_wT<<<80, 256, 0, stream>>>(wT, cgpad, n_nodes);
  compute_cT<<<(n_nodes + 3) / 4, 256, 0, stream>>>(wT, rowptr, edst, cT, n_nodes);
  ugemm<<<dim3(4, NCHUNK), 256, 0, stream>>>(x, cT, Upart);
  reduce_U<<<dim3(64, RSPLIT), 128, 0, stream>>>(Upart, Ured);

  // --- weight precompute: Q = [Wg2;bg2]@Wc1 ; P = [Wg1;bg1]@Q[0:512] ---
  gemm_stack<<<dim3(17, 4), 256, 0, stream>>>(Wg2, bg2, Wc1, Q, 513, 256, 512, 512);
  gemm_stack<<<dim3(17, 4), 256, 0, stream>>>(Wg1, bg1, Q, P, 513, 256, 512, 512);

  // --- head ---
  head<<<NG, 256, 0, stream>>>(Ured, P, Q, ng, cgpad, bc1, Wc2, bc2, out);
}

// Round 11
// 280.681 us; speedup vs baseline: 1.2507x; 1.1090x over previous
//
#include <hip/hip_runtime.h>
#include <math.h>

constexpr int N_NODES = 20000;
constexpr int DIM = 512;       // NODE_DIM == HIDDEN
constexpr int NG = 64;
constexpr int CAP = 64;        // padded adjacency capacity (avg deg 16, max ~40, >12 sigma)
constexpr int KCH = 128;       // U-GEMM k-chunk
constexpr int NCHUNK = (N_NODES + KCH - 1) / KCH;  // 157 (last chunk kmax=32, %4==0)
constexpr int RSPLIT = 4;
constexpr int CPS = (NCHUNK + RSPLIT - 1) / RSPLIT; // 40
constexpr int CGS = 32;        // cgpad stride (floats) -> 128B, one cacheline per graph

// ---------------- misc ----------------
__device__ __forceinline__ int lower_bound_i(const int* __restrict__ a, int n, int v) {
  int lo = 0, hi = n;
  while (lo < hi) {
    int mid = (lo + hi) >> 1;
    if (a[mid] < v) lo = mid + 1; else hi = mid;
  }
  return lo;
}

// cursor[j]=0 (grid-stride); block 0 also: ng[g] via binary search, cgpad zero
__global__ __launch_bounds__(256) void node_init(const int* __restrict__ batch,
                                                 int* __restrict__ cursor,
                                                 float* __restrict__ ng,
                                                 float* __restrict__ cgpad, int n_nodes) {
  int i = blockIdx.x * blockDim.x + threadIdx.x;
  int stride = gridDim.x * blockDim.x;
  for (; i < n_nodes; i += stride) cursor[i] = 0;
  if (blockIdx.x == 0 && threadIdx.x < 64) {
    int gg = threadIdx.x;
    int s0 = lower_bound_i(batch, n_nodes, gg);
    int e0 = lower_bound_i(batch, n_nodes, gg + 1);
    ng[gg] = (float)(e0 - s0);
    cgpad[gg * CGS] = 0.f;
  }
}

// padded adjacency fill: one atomic + one scattered 4B write per edge.
// cursor[s] ends up holding out-degree(s).
__global__ __launch_bounds__(256) void fill_pad(const int* __restrict__ srcI,
                                                const int* __restrict__ dstI,
                                                int* __restrict__ cursor,
                                                int* __restrict__ edst, int n_edges) {
  int i = blockIdx.x * 256 + threadIdx.x;
  if (i < n_edges) {
    int s = srcI[i];
    int c = atomicAdd(&cursor[s], 1);
    edst[(size_t)s * CAP + c] = dstI[i];
  }
}

// ---------------- wT[j][g] = [batch_j==g] + sum_{d in N(j)} [batch_d==g] ----------------
__global__ __launch_bounds__(256) void build_wT(const int* __restrict__ batch,
                                                const int* __restrict__ deg,
                                                const int* __restrict__ edst,
                                                float* __restrict__ wT, int n_nodes) {
  int node = blockIdx.x * 4 + (threadIdx.x >> 6);
  int g = threadIdx.x & 63;
  if (node >= n_nodes) return;
  int acc = (batch[node] == g) ? 1 : 0;
  int end = deg[node];
  const int* nb = edst + (size_t)node * CAP;
  int i = 0;
  for (; i + 3 < end; i += 4) {
    int d0 = nb[i], d1 = nb[i + 1], d2 = nb[i + 2], d3 = nb[i + 3];
    int b0 = batch[d0], b1 = batch[d1], b2 = batch[d2], b3 = batch[d3];
    acc += (b0 == g) + (b1 == g) + (b2 == g) + (b3 == g);
  }
  for (; i < end; ++i) acc += (batch[nb[i]] == g) ? 1 : 0;
  wT[(size_t)node * 64 + g] = (float)acc;
}

// ---------------- cg[g] = colsum(wT)[g] ----------------
// 80 blocks x (4 waves x 64 lanes); LDS reduce; padded atomics (1 line/graph, 80/line)
__global__ __launch_bounds__(256) void colsum_wT(const float* __restrict__ wT,
                                                 float* __restrict__ cgpad, int n_nodes) {
  int wave = threadIdx.x >> 6;
  int g = threadIdx.x & 63;
  float acc = 0.f;
  for (int node = blockIdx.x * 4 + wave; node < n_nodes; node += gridDim.x * 4)
    acc += wT[(size_t)node * 64 + g];
  __shared__ float s[4][64];
  s[wave][g] = acc;
  __syncthreads();
  if (wave == 0) {
    float v = s[0][g] + s[1][g] + s[2][g] + s[3][g];
    atomicAdd(&cgpad[g * CGS], v);
  }
}

// ---------------- cT[k][g] = wT[k][g] + sum_{d in N(k)} wT[d][g] (x4 unrolled) ----------------
__global__ __launch_bounds__(256) void compute_cT(const float* __restrict__ wT,
                                                  const int* __restrict__ deg,
                                                  const int* __restrict__ edst,
                                                  float* __restrict__ cT, int n_nodes) {
  int node = blockIdx.x * 4 + (threadIdx.x >> 6);
  int g = threadIdx.x & 63;
  if (node >= n_nodes) return;
  float acc = wT[(size_t)node * 64 + g];
  int end = deg[node];
  const int* nb = edst + (size_t)node * CAP;
  int i = 0;
  for (; i + 3 < end; i += 4) {
    int d0 = nb[i], d1 = nb[i + 1], d2 = nb[i + 2], d3 = nb[i + 3];
    acc += wT[(size_t)d0 * 64 + g] + wT[(size_t)d1 * 64 + g] +
           wT[(size_t)d2 * 64 + g] + wT[(size_t)d3 * 64 + g];
  }
  for (; i < end; ++i) acc += wT[(size_t)nb[i] * 64 + g];
  cT[(size_t)node * 64 + g] = acc;
}

// ---------------- U-GEMM: Upart[c][g][n] = sum_{k in chunk c} cT[k][g]*x[k][n] ----------------
__global__ __launch_bounds__(256) void ugemm(const float* __restrict__ x,
                                             const float* __restrict__ cT,
                                             float* __restrict__ Upart) {
  __shared__ float sc[KCH][64];  // 32 KB
  int t = threadIdx.x;
  int k0 = blockIdx.y * KCH;
  int kmax = (N_NODES - k0) < KCH ? (N_NODES - k0) : KCH;  // 128 or 32; %4==0
  {
    const float4* src = (const float4*)(cT + (size_t)k0 * 64);
    float4* dst = (float4*)(&sc[0][0]);
    int limit4 = kmax * 16;
    for (int i = t; i < limit4; i += 256) dst[i] = src[i];
  }
  __syncthreads();
  int lane = t & 63;
  int slice = t >> 6;                 // g-range [slice*16, slice*16+16)
  int n2 = blockIdx.x * 64 + lane;    // float2 col 0..255
  const float2* x2 = (const float2*)x;
  float2 acc[16];
#pragma unroll
  for (int j = 0; j < 16; ++j) acc[j] = make_float2(0.f, 0.f);
  for (int kk = 0; kk < kmax; kk += 4) {
    float2 xv[4];
#pragma unroll
    for (int u = 0; u < 4; ++u)
      xv[u] = x2[(size_t)(k0 + kk + u) * 256 + n2];
#pragma unroll
    for (int u = 0; u < 4; ++u) {
      const float4* cp = (const float4*)&sc[kk + u][slice * 16];
      float4 c0 = cp[0], c1 = cp[1], c2 = cp[2], c3 = cp[3];
      float2 xu = xv[u];
      acc[0].x  = fmaf(c0.x, xu.x, acc[0].x);  acc[0].y  = fmaf(c0.x, xu.y, acc[0].y);
      acc[1].x  = fmaf(c0.y, xu.x, acc[1].x);  acc[1].y  = fmaf(c0.y, xu.y, acc[1].y);
      acc[2].x  = fmaf(c0.z, xu.x, acc[2].x);  acc[2].y  = fmaf(c0.z, xu.y, acc[2].y);
      acc[3].x  = fmaf(c0.w, xu.x, acc[3].x);  acc[3].y  = fmaf(c0.w, xu.y, acc[3].y);
      acc[4].x  = fmaf(c1.x, xu.x, acc[4].x);  acc[4].y  = fmaf(c1.x, xu.y, acc[4].y);
      acc[5].x  = fmaf(c1.y, xu.x, acc[5].x);  acc[5].y  = fmaf(c1.y, xu.y, acc[5].y);
      acc[6].x  = fmaf(c1.z, xu.x, acc[6].x);  acc[6].y  = fmaf(c1.z, xu.y, acc[6].y);
      acc[7].x  = fmaf(c1.w, xu.x, acc[7].x);  acc[7].y  = fmaf(c1.w, xu.y, acc[7].y);
      acc[8].x  = fmaf(c2.x, xu.x, acc[8].x);  acc[8].y  = fmaf(c2.x, xu.y, acc[8].y);
      acc[9].x  = fmaf(c2.y, xu.x, acc[9].x);  acc[9].y  = fmaf(c2.y, xu.y, acc[9].y);
      acc[10].x = fmaf(c2.z, xu.x, acc[10].x); acc[10].y = fmaf(c2.z, xu.y, acc[10].y);
      acc[11].x = fmaf(c2.w, xu.x, acc[11].x); acc[11].y = fmaf(c2.w, xu.y, acc[11].y);
      acc[12].x = fmaf(c3.x, xu.x, acc[12].x); acc[12].y = fmaf(c3.x, xu.y, acc[12].y);
      acc[13].x = fmaf(c3.y, xu.x, acc[13].x); acc[13].y = fmaf(c3.y, xu.y, acc[13].y);
      acc[14].x = fmaf(c3.z, xu.x, acc[14].x); acc[14].y = fmaf(c3.z, xu.y, acc[14].y);
      acc[15].x = fmaf(c3.w, xu.x, acc[15].x); acc[15].y = fmaf(c3.w, xu.y, acc[15].y);
    }
  }
  float2* up = (float2*)Upart;
#pragma unroll
  for (int j = 0; j < 16; ++j) {
    int g = slice * 16 + j;
    up[((size_t)blockIdx.y * 64 + g) * 256 + n2] = acc[j];
  }
}

// ---------------- Upart reduce: Ured[s][g][n] = sum_{c in split s} Upart[c][g][n] ----------------
__global__ __launch_bounds__(128) void reduce_U(const float* __restrict__ Upart,
                                                float* __restrict__ Ured) {
  int g = blockIdx.x;   // 0..63
  int s = blockIdx.y;   // 0..RSPLIT-1
  int t = threadIdx.x;  // 0..127 float4 over 512
  int c0 = s * CPS;
  int c1 = (c0 + CPS < NCHUNK) ? c0 + CPS : NCHUNK;
  const float4* up = (const float4*)Upart;
  float4 acc = make_float4(0.f, 0.f, 0.f, 0.f);
  for (int c = c0; c < c1; ++c) {
    float4 v = up[((size_t)c * 64 + g) * 128 + t];
    acc.x += v.x; acc.y += v.y; acc.z += v.z; acc.w += v.w;
  }
  ((float4*)Ured)[((size_t)s * 64 + g) * 128 + t] = acc;
}

// ---------------- stacked-row fp32 GEMM: C[M,N] = [A0; extraRow] @ B ----------------
__global__ __launch_bounds__(256) void gemm_stack(const float* __restrict__ A0,
                                                  const float* __restrict__ extra,
                                                  const float* __restrict__ B,
                                                  float* __restrict__ C,
                                                  int M, int N, int K, int R0) {
  __shared__ float As[16][33];
  __shared__ float Bs[16][65];
  int tid = threadIdx.x;
  int tx = tid & 15;
  int ty = tid >> 4;
  int bm = blockIdx.x * 32;
  int bn = blockIdx.y * 64;

  int ar = tid >> 3;        // 0..31 : A row in tile
  int ac = (tid & 7) * 2;   // 0..14 : k offset (float2)
  int br = tid >> 4;        // 0..15 : B k row
  int bc = (tid & 15) * 4;  // B col offset (float4)

  float acc[2][4] = {};

  for (int k0 = 0; k0 < K; k0 += 16) {
    int row = bm + ar;
    float2 av = make_float2(0.f, 0.f);
    if (row < R0)       av = *(const float2*)(A0 + (size_t)row * K + k0 + ac);
    else if (row == R0) av = *(const float2*)(extra + k0 + ac);
    As[ac + 0][ar] = av.x;
    As[ac + 1][ar] = av.y;
    float4 bv = *(const float4*)(B + (size_t)(k0 + br) * N + bn + bc);
    Bs[br][bc + 0] = bv.x;
    Bs[br][bc + 1] = bv.y;
    Bs[br][bc + 2] = bv.z;
    Bs[br][bc + 3] = bv.w;
    __syncthreads();
#pragma unroll
    for (int kk = 0; kk < 16; ++kk) {
      float a0 = As[kk][ty * 2 + 0];
      float a1 = As[kk][ty * 2 + 1];
      float b0 = Bs[kk][tx * 4 + 0];
      float b1 = Bs[kk][tx * 4 + 1];
      float b2 = Bs[kk][tx * 4 + 2];
      float b3 = Bs[kk][tx * 4 + 3];
      acc[0][0] = fmaf(a0, b0, acc[0][0]); acc[0][1] = fmaf(a0, b1, acc[0][1]);
      acc[0][2] = fmaf(a0, b2, acc[0][2]); acc[0][3] = fmaf(a0, b3, acc[0][3]);
      acc[1][0] = fmaf(a1, b0, acc[1][0]); acc[1][1] = fmaf(a1, b1, acc[1][1]);
      acc[1][2] = fmaf(a1, b2, acc[1][2]); acc[1][3] = fmaf(a1, b3, acc[1][3]);
    }
    __syncthreads();
  }

#pragma unroll
  for (int i = 0; i < 2; ++i) {
    int m = bm + ty * 2 + i;
    if (m >= M) continue;
#pragma unroll
    for (int j = 0; j < 4; ++j) {
      C[(size_t)m * N + bn + tx * 4 + j] = acc[i][j];
    }
  }
}

// ---------------- fused head ----------------
// P[0:512] = Wc, P[512] = v1 ; Q[512] = v2 ; cg from cgpad
__global__ __launch_bounds__(256) void head(const float* __restrict__ Ured,
                                            const float* __restrict__ P,
                                            const float* __restrict__ Q,
                                            const float* __restrict__ ng,
                                            const float* __restrict__ cgpad,
                                            const float* __restrict__ bc1,
                                            const float* __restrict__ Wc2,
                                            const float* __restrict__ bc2,
                                            float* __restrict__ out) {
  int g = blockIdx.x;
  int j = threadIdx.x;
  const float* Wc = P;
  const float* v1 = P + (size_t)512 * 256;
  const float* v2 = Q + (size_t)512 * 256;
  __shared__ float p[512];
  float s0 = 0.f, s1 = 0.f;
#pragma unroll
  for (int s = 0; s < RSPLIT; ++s) {
    s0 += Ured[((size_t)s * 64 + g) * DIM + j];
    s1 += Ured[((size_t)s * 64 + g) * DIM + 256 + j];
  }
  p[j] = s0;
  p[j + 256] = s1;
  __syncthreads();
  float cg = cgpad[g * CGS];
  float acc = bc1[j] + cg * v1[j] + ng[g] * v2[j];
  for (int k = 0; k < 512; ++k) acc = fmaf(p[k], Wc[k * 256 + j], acc);
  float z = fmaxf(acc, 0.f);
  float part = z * Wc2[j];
  for (int off = 32; off > 0; off >>= 1) part += __shfl_down(part, off, 64);
  __shared__ float red[4];
  if ((j & 63) == 0) red[j >> 6] = part;
  __syncthreads();
  if (j == 0) {
    float tot = red[0] + red[1] + red[2] + red[3] + bc2[0];
    out[g] = 1.f / (1.f + expf(-tot));
  }
}

extern "C" void kernel_launch(void* const* d_in, const int* in_sizes, int n_in,
                              void* d_out, int out_size, void* d_ws, size_t ws_size,
                              hipStream_t stream) {
  const float* x    = (const float*)d_in[0];
  const int*   ei   = (const int*)d_in[1];
  const int*   batch= (const int*)d_in[2];
  const float* Wg1  = (const float*)d_in[3];
  const float* bg1  = (const float*)d_in[4];
  const float* Wg2  = (const float*)d_in[5];
  const float* bg2  = (const float*)d_in[6];
  const float* Wc1  = (const float*)d_in[7];
  const float* bc1  = (const float*)d_in[8];
  const float* Wc2  = (const float*)d_in[9];
  const float* bc2  = (const float*)d_in[10];
  float* out = (float*)d_out;

  int n_edges = in_sizes[1] / 2;
  int n_nodes = in_sizes[2];
  const int* srcI = ei;
  const int* dstI = ei + n_edges;

  char* ws = (char*)d_ws;
  size_t off = 0;
  auto alloc = [&](size_t bytes) { char* p = ws + off; off += (bytes + 255) & ~(size_t)255; return p; };
  float* wT    = (float*)alloc((size_t)N_NODES * 64 * sizeof(float));        // 5.12 MB
  float* cT    = (float*)alloc((size_t)N_NODES * 64 * sizeof(float));        // 5.12 MB
  float* Upart = (float*)alloc((size_t)NCHUNK * 64 * DIM * sizeof(float));   // 20.6 MB
  float* Ured  = (float*)alloc((size_t)RSPLIT * 64 * DIM * sizeof(float));   // 512 KB
  float* Q     = (float*)alloc((size_t)513 * 256 * sizeof(float));           // [Wg2;bg2]@Wc1
  float* P     = (float*)alloc((size_t)513 * 256 * sizeof(float));           // [Wg1;bg1]@Q0
  float* ng    = (float*)alloc(NG * sizeof(float));
  float* cgpad = (float*)alloc(NG * CGS * sizeof(float));
  int* cursor  = (int*)alloc(N_NODES * sizeof(int));                         // degree after fill
  int* edst    = (int*)alloc((size_t)N_NODES * CAP * sizeof(int));           // 5.12 MB padded adj

  // --- padded adjacency build (no count pass, no scan) ---
  node_init<<<80, 256, 0, stream>>>(batch, cursor, ng, cgpad, n_nodes);
  fill_pad<<<(n_edges + 255) / 256, 256, 0, stream>>>(srcI, dstI, cursor, edst, n_edges);

  // --- coefficients (atomic-free gathers) + cg colsum + U = cT^T @ x ---
  build_wT<<<(n_nodes + 3) / 4, 256, 0, stream>>>(batch, cursor, edst, wT, n_nodes);
  colsum_wT<<<80, 256, 0, stream>>>(wT, cgpad, n_nodes);
  compute_cT<<<(n_nodes + 3) / 4, 256, 0, stream>>>(wT, cursor, edst, cT, n_nodes);
  ugemm<<<dim3(4, NCHUNK), 256, 0, stream>>>(x, cT, Upart);
  reduce_U<<<dim3(64, RSPLIT), 128, 0, stream>>>(Upart, Ured);

  // --- weight precompute: Q = [Wg2;bg2]@Wc1 ; P = [Wg1;bg1]@Q[0:512] ---
  gemm_stack<<<dim3(17, 4), 256, 0, stream>>>(Wg2, bg2, Wc1, Q, 513, 256, 512, 512);
  gemm_stack<<<dim3(17, 4), 256, 0, stream>>>(Wg1, bg1, Q, P, 513, 256, 512, 512);

  // --- head ---
  head<<<NG, 256, 0, stream>>>(Ured, P, Q, ng, cgpad, bc1, Wc2, bc2, out);
}

// Round 13
// 270.465 us; speedup vs baseline: 1.2979x; 1.0378x over previous
//
#include <hip/hip_runtime.h>
#include <math.h>

constexpr int N_NODES = 20000;
constexpr int DIM = 512;       // NODE_DIM == HIDDEN
constexpr int NG = 64;
constexpr int CAP = 64;        // padded adjacency capacity (avg deg 16, max ~40, >12 sigma)
constexpr int KCH = 128;       // U-GEMM k-chunk
constexpr int NCHUNK = (N_NODES + KCH - 1) / KCH;  // 157 (last chunk kmax=32, %4==0)
constexpr int RSPLIT = 4;
constexpr int CPS = (NCHUNK + RSPLIT - 1) / RSPLIT; // 40
constexpr int CGS = 32;        // cgpad stride (floats) -> 128B, one cacheline per graph
constexpr int NODE_BLOCKS = (N_NODES + 3) / 4;      // 5000
constexpr int GEMM_TILES = 17 * 4;                  // 68 tiles for 513x256 output

// ---------------- misc ----------------
__device__ __forceinline__ int lower_bound_i(const int* __restrict__ a, int n, int v) {
  int lo = 0, hi = n;
  while (lo < hi) {
    int mid = (lo + hi) >> 1;
    if (a[mid] < v) lo = mid + 1; else hi = mid;
  }
  return lo;
}

// cursor[j]=0 (grid-stride); block 0 also: ng[g] via binary search, cgpad zero
__global__ __launch_bounds__(256) void node_init(const int* __restrict__ batch,
                                                 int* __restrict__ cursor,
                                                 float* __restrict__ ng,
                                                 float* __restrict__ cgpad, int n_nodes) {
  int i = blockIdx.x * blockDim.x + threadIdx.x;
  int stride = gridDim.x * blockDim.x;
  for (; i < n_nodes; i += stride) cursor[i] = 0;
  if (blockIdx.x == 0 && threadIdx.x < 64) {
    int gg = threadIdx.x;
    int s0 = lower_bound_i(batch, n_nodes, gg);
    int e0 = lower_bound_i(batch, n_nodes, gg + 1);
    ng[gg] = (float)(e0 - s0);
    cgpad[gg * CGS] = 0.f;
  }
}

// padded adjacency fill + per-graph incoming-edge histogram.
// cursor[s] ends up as out-degree(s); cgpad[g*CGS] accumulates edge count into graph g.
__global__ __launch_bounds__(256) void fill_pad_hist(const int* __restrict__ srcI,
                                                     const int* __restrict__ dstI,
                                                     const int* __restrict__ batch,
                                                     int* __restrict__ cursor,
                                                     int* __restrict__ edst,
                                                     float* __restrict__ cgpad, int n_edges) {
  __shared__ int hist[64];
  int t = threadIdx.x;
  if (t < 64) hist[t] = 0;
  __syncthreads();
  int stride = gridDim.x * 256;
  for (int i = blockIdx.x * 256 + t; i < n_edges; i += stride) {
    int s = srcI[i];
    int d = dstI[i];
    int c = atomicAdd(&cursor[s], 1);
    edst[(size_t)s * CAP + c] = d;
    atomicAdd(&hist[batch[d]], 1);
  }
  __syncthreads();
  if (t < 64 && hist[t] != 0) atomicAdd(&cgpad[t * CGS], (float)hist[t]);
}

// ---- shared-memory GEMM tile body: C[M,N] = [A0; extraRow] @ B, one 32x64 tile ----
__device__ void gemm_stack_tile(const float* __restrict__ A0, const float* __restrict__ extra,
                                const float* __restrict__ B, float* __restrict__ C,
                                int M, int N, int K, int R0, int tile,
                                float* As, float* Bs, int tid) {
  int bm = (tile >> 2) * 32;   // 0..16 -> 32-row tile
  int bn = (tile & 3) * 64;    // 0..3  -> 64-col tile
  int tx = tid & 15;
  int ty = tid >> 4;
  int ar = tid >> 3;
  int ac = (tid & 7) * 2;
  int br = tid >> 4;
  int bc = (tid & 15) * 4;
  float acc[2][4] = {};
  for (int k0 = 0; k0 < K; k0 += 16) {
    int row = bm + ar;
    float2 av = make_float2(0.f, 0.f);
    if (row < R0)       av = *(const float2*)(A0 + (size_t)row * K + k0 + ac);
    else if (row == R0) av = *(const float2*)(extra + k0 + ac);
    As[(ac + 0) * 33 + ar] = av.x;
    As[(ac + 1) * 33 + ar] = av.y;
    float4 bv = *(const float4*)(B + (size_t)(k0 + br) * N + bn + bc);
    Bs[br * 65 + bc + 0] = bv.x;
    Bs[br * 65 + bc + 1] = bv.y;
    Bs[br * 65 + bc + 2] = bv.z;
    Bs[br * 65 + bc + 3] = bv.w;
    __syncthreads();
#pragma unroll
    for (int kk = 0; kk < 16; ++kk) {
      float a0 = As[kk * 33 + ty * 2 + 0];
      float a1 = As[kk * 33 + ty * 2 + 1];
      float b0 = Bs[kk * 65 + tx * 4 + 0];
      float b1 = Bs[kk * 65 + tx * 4 + 1];
      float b2 = Bs[kk * 65 + tx * 4 + 2];
      float b3 = Bs[kk * 65 + tx * 4 + 3];
      acc[0][0] = fmaf(a0, b0, acc[0][0]); acc[0][1] = fmaf(a0, b1, acc[0][1]);
      acc[0][2] = fmaf(a0, b2, acc[0][2]); acc[0][3] = fmaf(a0, b3, acc[0][3]);
      acc[1][0] = fmaf(a1, b0, acc[1][0]); acc[1][1] = fmaf(a1, b1, acc[1][1]);
      acc[1][2] = fmaf(a1, b2, acc[1][2]); acc[1][3] = fmaf(a1, b3, acc[1][3]);
    }
    __syncthreads();
  }
#pragma unroll
  for (int i = 0; i < 2; ++i) {
    int m = bm + ty * 2 + i;
    if (m >= M) continue;
#pragma unroll
    for (int j = 0; j < 4; ++j) {
      C[(size_t)m * N + bn + tx * 4 + j] = acc[i][j];
    }
  }
}

// ---------------- K3: build_wT (blocks < NODE_BLOCKS)  ||  Q = [Wg2;bg2]@Wc1 ----------------
__global__ __launch_bounds__(256) void wT_and_Q(const int* __restrict__ batch,
                                                const int* __restrict__ deg,
                                                const int* __restrict__ edst,
                                                float* __restrict__ wT,
                                                const float* __restrict__ Wg2,
                                                const float* __restrict__ bg2,
                                                const float* __restrict__ Wc1,
                                                float* __restrict__ Q, int n_nodes) {
  __shared__ float As[16 * 33];
  __shared__ float Bs[16 * 65];
  int b = blockIdx.x;
  if (b < NODE_BLOCKS) {
    int node = b * 4 + (threadIdx.x >> 6);
    int g = threadIdx.x & 63;
    if (node >= n_nodes) return;
    int acc = (batch[node] == g) ? 1 : 0;
    int end = deg[node];
    const int* nb = edst + (size_t)node * CAP;
    int i = 0;
    for (; i + 3 < end; i += 4) {
      int d0 = nb[i], d1 = nb[i + 1], d2 = nb[i + 2], d3 = nb[i + 3];
      acc += (batch[d0] == g) + (batch[d1] == g) + (batch[d2] == g) + (batch[d3] == g);
    }
    for (; i < end; ++i) acc += (batch[nb[i]] == g) ? 1 : 0;
    wT[(size_t)node * 64 + g] = (float)acc;
  } else {
    gemm_stack_tile(Wg2, bg2, Wc1, Q, 513, 256, 512, 512, b - NODE_BLOCKS, As, Bs, threadIdx.x);
  }
}

// ---------------- K4: compute_cT (blocks < NODE_BLOCKS)  ||  P = [Wg1;bg1]@Q[0:512] ----------------
__global__ __launch_bounds__(256) void cT_and_P(const float* __restrict__ wT,
                                                const int* __restrict__ deg,
                                                const int* __restrict__ edst,
                                                float* __restrict__ cT,
                                                const float* __restrict__ Wg1,
                                                const float* __restrict__ bg1,
                                                const float* __restrict__ Q,
                                                float* __restrict__ P, int n_nodes) {
  __shared__ float As[16 * 33];
  __shared__ float Bs[16 * 65];
  int b = blockIdx.x;
  if (b < NODE_BLOCKS) {
    int node = b * 4 + (threadIdx.x >> 6);
    int g = threadIdx.x & 63;
    if (node >= n_nodes) return;
    float acc = wT[(size_t)node * 64 + g];
    int end = deg[node];
    const int* nb = edst + (size_t)node * CAP;
    int i = 0;
    for (; i + 3 < end; i += 4) {
      int d0 = nb[i], d1 = nb[i + 1], d2 = nb[i + 2], d3 = nb[i + 3];
      acc += wT[(size_t)d0 * 64 + g] + wT[(size_t)d1 * 64 + g] +
             wT[(size_t)d2 * 64 + g] + wT[(size_t)d3 * 64 + g];
    }
    for (; i < end; ++i) acc += wT[(size_t)nb[i] * 64 + g];
    cT[(size_t)node * 64 + g] = acc;
  } else {
    gemm_stack_tile(Wg1, bg1, Q, P, 513, 256, 512, 512, b - NODE_BLOCKS, As, Bs, threadIdx.x);
  }
}

// ---------------- U-GEMM: Upart[c][g][n] = sum_{k in chunk c} cT[k][g]*x[k][n] ----------------
__global__ __launch_bounds__(256) void ugemm(const float* __restrict__ x,
                                             const float* __restrict__ cT,
                                             float* __restrict__ Upart) {
  __shared__ float sc[KCH][64];  // 32 KB
  int t = threadIdx.x;
  int k0 = blockIdx.y * KCH;
  int kmax = (N_NODES - k0) < KCH ? (N_NODES - k0) : KCH;  // 128 or 32; %4==0
  {
    const float4* src = (const float4*)(cT + (size_t)k0 * 64);
    float4* dst = (float4*)(&sc[0][0]);
    int limit4 = kmax * 16;
    for (int i = t; i < limit4; i += 256) dst[i] = src[i];
  }
  __syncthreads();
  int lane = t & 63;
  int slice = t >> 6;                 // g-range [slice*16, slice*16+16)
  int n2 = blockIdx.x * 64 + lane;    // float2 col 0..255
  const float2* x2 = (const float2*)x;
  float2 acc[16];
#pragma unroll
  for (int j = 0; j < 16; ++j) acc[j] = make_float2(0.f, 0.f);
  for (int kk = 0; kk < kmax; kk += 4) {
    float2 xv[4];
#pragma unroll
    for (int u = 0; u < 4; ++u)
      xv[u] = x2[(size_t)(k0 + kk + u) * 256 + n2];
#pragma unroll
    for (int u = 0; u < 4; ++u) {
      const float4* cp = (const float4*)&sc[kk + u][slice * 16];
      float4 c0 = cp[0], c1 = cp[1], c2 = cp[2], c3 = cp[3];
      float2 xu = xv[u];
      acc[0].x  = fmaf(c0.x, xu.x, acc[0].x);  acc[0].y  = fmaf(c0.x, xu.y, acc[0].y);
      acc[1].x  = fmaf(c0.y, xu.x, acc[1].x);  acc[1].y  = fmaf(c0.y, xu.y, acc[1].y);
      acc[2].x  = fmaf(c0.z, xu.x, acc[2].x);  acc[2].y  = fmaf(c0.z, xu.y, acc[2].y);
      acc[3].x  = fmaf(c0.w, xu.x, acc[3].x);  acc[3].y  = fmaf(c0.w, xu.y, acc[3].y);
      acc[4].x  = fmaf(c1.x, xu.x, acc[4].x);  acc[4].y  = fmaf(c1.x, xu.y, acc[4].y);
      acc[5].x  = fmaf(c1.y, xu.x, acc[5].x);  acc[5].y  = fmaf(c1.y, xu.y, acc[5].y);
      acc[6].x  = fmaf(c1.z, xu.x, acc[6].x);  acc[6].y  = fmaf(c1.z, xu.y, acc[6].y);
      acc[7].x  = fmaf(c1.w, xu.x, acc[7].x);  acc[7].y  = fmaf(c1.w, xu.y, acc[7].y);
      acc[8].x  = fmaf(c2.x, xu.x, acc[8].x);  acc[8].y  = fmaf(c2.x, xu.y, acc[8].y);
      acc[9].x  = fmaf(c2.y, xu.x, acc[9].x);  acc[9].y  = fmaf(c2.y, xu.y, acc[9].y);
      acc[10].x = fmaf(c2.z, xu.x, acc[10].x); acc[10].y = fmaf(c2.z, xu.y, acc[10].y);
      acc[11].x = fmaf(c2.w, xu.x, acc[11].x); acc[11].y = fmaf(c2.w, xu.y, acc[11].y);
      acc[12].x = fmaf(c3.x, xu.x, acc[12].x); acc[12].y = fmaf(c3.x, xu.y, acc[12].y);
      acc[13].x = fmaf(c3.y, xu.x, acc[13].x); acc[13].y = fmaf(c3.y, xu.y, acc[13].y);
      acc[14].x = fmaf(c3.z, xu.x, acc[14].x); acc[14].y = fmaf(c3.z, xu.y, acc[14].y);
      acc[15].x = fmaf(c3.w, xu.x, acc[15].x); acc[15].y = fmaf(c3.w, xu.y, acc[15].y);
    }
  }
  float2* up = (float2*)Upart;
#pragma unroll
  for (int j = 0; j < 16; ++j) {
    int g = slice * 16 + j;
    up[((size_t)blockIdx.y * 64 + g) * 256 + n2] = acc[j];
  }
}

// ---------------- Upart reduce: Ured[s][g][n] = sum_{c in split s} Upart[c][g][n] ----------------
__global__ __launch_bounds__(128) void reduce_U(const float* __restrict__ Upart,
                                                float* __restrict__ Ured) {
  int g = blockIdx.x;   // 0..63
  int s = blockIdx.y;   // 0..RSPLIT-1
  int t = threadIdx.x;  // 0..127 float4 over 512
  int c0 = s * CPS;
  int c1 = (c0 + CPS < NCHUNK) ? c0 + CPS : NCHUNK;
  const float4* up = (const float4*)Upart;
  float4 acc = make_float4(0.f, 0.f, 0.f, 0.f);
  for (int c = c0; c < c1; ++c) {
    float4 v = up[((size_t)c * 64 + g) * 128 + t];
    acc.x += v.x; acc.y += v.y; acc.z += v.z; acc.w += v.w;
  }
  ((float4*)Ured)[((size_t)s * 64 + g) * 128 + t] = acc;
}

// ---------------- fused head ----------------
// P[0:512] = Wc, P[512] = v1 ; Q[512] = v2 ; cg = ng + edge-hist(cgpad)
__global__ __launch_bounds__(256) void head(const float* __restrict__ Ured,
                                            const float* __restrict__ P,
                                            const float* __restrict__ Q,
                                            const float* __restrict__ ng,
                                            const float* __restrict__ cgpad,
                                            const float* __restrict__ bc1,
                                            const float* __restrict__ Wc2,
                                            const float* __restrict__ bc2,
                                            float* __restrict__ out) {
  int g = blockIdx.x;
  int j = threadIdx.x;
  const float* Wc = P;
  const float* v1 = P + (size_t)512 * 256;
  const float* v2 = Q + (size_t)512 * 256;
  __shared__ float p[512];
  float s0 = 0.f, s1 = 0.f;
#pragma unroll
  for (int s = 0; s < RSPLIT; ++s) {
    s0 += Ured[((size_t)s * 64 + g) * DIM + j];
    s1 += Ured[((size_t)s * 64 + g) * DIM + 256 + j];
  }
  p[j] = s0;
  p[j + 256] = s1;
  __syncthreads();
  float cg = ng[g] + cgpad[g * CGS];
  float acc = bc1[j] + cg * v1[j] + ng[g] * v2[j];
  for (int k = 0; k < 512; ++k) acc = fmaf(p[k], Wc[k * 256 + j], acc);
  float z = fmaxf(acc, 0.f);
  float part = z * Wc2[j];
  for (int off = 32; off > 0; off >>= 1) part += __shfl_down(part, off, 64);
  __shared__ float red[4];
  if ((j & 63) == 0) red[j >> 6] = part;
  __syncthreads();
  if (j == 0) {
    float tot = red[0] + red[1] + red[2] + red[3] + bc2[0];
    out[g] = 1.f / (1.f + expf(-tot));
  }
}

extern "C" void kernel_launch(void* const* d_in, const int* in_sizes, int n_in,
                              void* d_out, int out_size, void* d_ws, size_t ws_size,
                              hipStream_t stream) {
  const float* x    = (const float*)d_in[0];
  const int*   ei   = (const int*)d_in[1];
  const int*   batch= (const int*)d_in[2];
  const float* Wg1  = (const float*)d_in[3];
  const float* bg1  = (const float*)d_in[4];
  const float* Wg2  = (const float*)d_in[5];
  const float* bg2  = (const float*)d_in[6];
  const float* Wc1  = (const float*)d_in[7];
  const float* bc1  = (const float*)d_in[8];
  const float* Wc2  = (const float*)d_in[9];
  const float* bc2  = (const float*)d_in[10];
  float* out = (float*)d_out;

  int n_edges = in_sizes[1] / 2;
  int n_nodes = in_sizes[2];
  const int* srcI = ei;
  const int* dstI = ei + n_edges;

  char* ws = (char*)d_ws;
  size_t off = 0;
  auto alloc = [&](size_t bytes) { char* p = ws + off; off += (bytes + 255) & ~(size_t)255; return p; };
  float* wT    = (float*)alloc((size_t)N_NODES * 64 * sizeof(float));        // 5.12 MB
  float* cT    = (float*)alloc((size_t)N_NODES * 64 * sizeof(float));        // 5.12 MB
  float* Upart = (float*)alloc((size_t)NCHUNK * 64 * DIM * sizeof(float));   // 20.6 MB
  float* Ured  = (float*)alloc((size_t)RSPLIT * 64 * DIM * sizeof(float));   // 512 KB
  float* Q     = (float*)alloc((size_t)513 * 256 * sizeof(float));           // [Wg2;bg2]@Wc1
  float* P     = (float*)alloc((size_t)513 * 256 * sizeof(float));           // [Wg1;bg1]@Q0
  float* ng    = (float*)alloc(NG * sizeof(float));
  float* cgpad = (float*)alloc(NG * CGS * sizeof(float));
  int* cursor  = (int*)alloc(N_NODES * sizeof(int));                         // degree after fill
  int* edst    = (int*)alloc((size_t)N_NODES * CAP * sizeof(int));           // 5.12 MB padded adj

  // K1: init
  node_init<<<80, 256, 0, stream>>>(batch, cursor, ng, cgpad, n_nodes);
  // K2: padded adjacency + cg edge-hist
  fill_pad_hist<<<640, 256, 0, stream>>>(srcI, dstI, batch, cursor, edst, cgpad, n_edges);
  // K3: build_wT || Q = [Wg2;bg2]@Wc1
  wT_and_Q<<<NODE_BLOCKS + GEMM_TILES, 256, 0, stream>>>(batch, cursor, edst, wT,
                                                         Wg2, bg2, Wc1, Q, n_nodes);
  // K4: compute_cT || P = [Wg1;bg1]@Q[0:512]
  cT_and_P<<<NODE_BLOCKS + GEMM_TILES, 256, 0, stream>>>(wT, cursor, edst, cT,
                                                         Wg1, bg1, Q, P, n_nodes);
  // K5: U partials
  ugemm<<<dim3(4, NCHUNK), 256, 0, stream>>>(x, cT, Upart);
  // K6: reduce partials
  reduce_U<<<dim3(64, RSPLIT), 128, 0, stream>>>(Upart, Ured);
  // K7: head
  head<<<NG, 256, 0, stream>>>(Ured, P, Q, ng, cgpad, bc1, Wc2, bc2, out);
}